// Round 2
// baseline (429.773 us; speedup 1.0000x reference)
//
#include <hip/hip_runtime.h>

#define VOCAB   50000
#define EMBED   128
#define NTOT    200000
#define BATCH   1024
#define NTILE   128
#define NBLKS   1563          // ceil(NTOT/NTILE); last tile has 64 valid cols
#define MCHUNK  128
#define NCHUNKS 8             // BATCH / MCHUNK
#define TILE_B  32768         // NTILE*EMBED*2 bytes (bf16, swizzled)

typedef __attribute__((ext_vector_type(8))) __bf16 bf16x8;
typedef __attribute__((ext_vector_type(4))) float f32x4;

// global -> LDS direct copy, 16B per lane; linear LDS dest (rule #21)
#define GLOAD16(gp, lp) __builtin_amdgcn_global_load_lds( \
    (const __attribute__((address_space(1))) unsigned int*)(gp), \
    (__attribute__((address_space(3))) unsigned int*)(lp), 16, 0, 0)

__device__ __forceinline__ unsigned int f2bf(float f) {
  unsigned int u = __float_as_uint(f);
  u += 0x7FFFu + ((u >> 16) & 1u);   // RNE
  return u >> 16;
}

// h[b][e] = bf16(relu(W1[e][idx[b]])), written pre-swizzled in chunk tiles:
// [chunk][128 rows][256B], 16B unit p at byte ((p*16) ^ ((r&7)<<4))
__global__ void build_h_kernel(const int* __restrict__ idx,
                               const float* __restrict__ W1,
                               unsigned short* __restrict__ hws) {
  int u = blockIdx.x * 256 + threadIdx.x;   // 16384 units of 16B
  int b = u >> 4, p = u & 15;
  int id = idx[b];
  unsigned int w[4];
  #pragma unroll
  for (int k = 0; k < 4; ++k) {
    float v0 = W1[(size_t)(p * 8 + 2 * k) * VOCAB + id];
    float v1 = W1[(size_t)(p * 8 + 2 * k + 1) * VOCAB + id];
    w[k] = f2bf(fmaxf(v0, 0.f)) | (f2bf(fmaxf(v1, 0.f)) << 16);
  }
  int chunk = b >> 7, r = b & 127;
  size_t byte = (size_t)chunk * TILE_B + r * 256 + ((p * 16) ^ ((r & 7) << 4));
  *(uint4*)((char*)hws + byte) = make_uint4(w[0], w[1], w[2], w[3]);
}

// PASS==1: row sums of exp(logits) -> partial[nb*BATCH + m]; (WS2) also writes
//          converted bf16 swizzled W2 tile to w2ws for pass 2.
// PASS==2: out[m][n] = lse[m] - logit[m][n]  (nontemporal stores).
template <int PASS, bool WS2>
__global__ __launch_bounds__(256, 2)
void gemm_pass(const float* __restrict__ W2,
               const unsigned short* __restrict__ hws,
               unsigned short* __restrict__ w2ws,
               float* __restrict__ partial,
               const float* __restrict__ lse,
               float* __restrict__ out) {
  __shared__ __align__(16) char wt[TILE_B];     // W2 tile: 128 x 256B swz
  __shared__ __align__(16) char ht[TILE_B];     // h chunk: 128 x 256B swz
  __shared__ float part[MCHUNK][8];             // pass1 partial exp-sums
  __shared__ float lse_s[MCHUNK];               // pass2 lse cache

  const int t    = threadIdx.x;
  const int nb   = blockIdx.x;
  const int n0   = nb * NTILE;
  const int lane = t & 63;
  const int wid  = t >> 6;
  const int wm   = wid >> 1, wn = wid & 1;      // 2x2 waves, 64x64 each
  const int kg   = lane >> 4, rl = lane & 15;
  const bool edge = (n0 + NTILE > NTOT);

  // ---- stage W2 tile (once per block) ----
  if (PASS == 1 || !WS2) {
    // f32 -> bf16 convert + swizzled ds_write; pass1 also writes w2ws
    #pragma unroll
    for (int i = 0; i < 16; ++i) {
      int u = t + 256 * i;                       // 4096 float4 units
      int r = u >> 5, p8 = u & 31;
      int srow = (n0 + r < NTOT) ? (n0 + r) : (NTOT - 1);
      const float4 v = *(const float4*)(W2 + (size_t)srow * EMBED + p8 * 4);
      uint2 d;
      d.x = f2bf(v.x) | (f2bf(v.y) << 16);
      d.y = f2bf(v.z) | (f2bf(v.w) << 16);
      int byte = r * 256 + ((p8 * 8) ^ ((r & 7) << 4));
      *(uint2*)(wt + byte) = d;
      if (PASS == 1 && WS2)
        *(uint2*)((char*)w2ws + (size_t)nb * TILE_B + byte) = d;
    }
  } else {
    // pass2: direct bf16 copy from pre-swizzled ws into wt
    const char* src = (const char*)w2ws + (size_t)nb * TILE_B;
    #pragma unroll
    for (int i = 0; i < 8; ++i) {
      int off = (t + 256 * i) * 16;
      GLOAD16(src + off, wt + off);
    }
  }

  for (int c = 0; c < NCHUNKS; ++c) {
    __syncthreads();   // prev chunk consumed (and covers wt stage for c==0)

    // stage h chunk c (pre-swizzled in ws -> linear copy)
    {
      const char* src = (const char*)hws + (size_t)c * TILE_B;
      #pragma unroll
      for (int i = 0; i < 8; ++i) {
        int off = (t + 256 * i) * 16;
        GLOAD16(src + off, ht + off);
      }
    }
    if (PASS == 2) { if (t < MCHUNK) lse_s[t] = lse[c * MCHUNK + t]; }
    __syncthreads();

    f32x4 acc[4][4];
    #pragma unroll
    for (int a = 0; a < 4; ++a)
      #pragma unroll
      for (int b = 0; b < 4; ++b)
        acc[a][b] = (f32x4){0.f, 0.f, 0.f, 0.f};

    #pragma unroll
    for (int kk = 0; kk < 4; ++kk) {
      const int kb = kk * 64 + kg * 16;
      bf16x8 af[4], bf_[4];
      #pragma unroll
      for (int fm = 0; fm < 4; ++fm) {
        int r = wm * 64 + fm * 16 + rl;
        af[fm] = *(const bf16x8*)(ht + r * 256 + (kb ^ ((r & 7) << 4)));
      }
      #pragma unroll
      for (int fn = 0; fn < 4; ++fn) {
        int r = wn * 64 + fn * 16 + rl;
        bf_[fn] = *(const bf16x8*)(wt + r * 256 + (kb ^ ((r & 7) << 4)));
      }
      #pragma unroll
      for (int fm = 0; fm < 4; ++fm)
        #pragma unroll
        for (int fn = 0; fn < 4; ++fn)
          acc[fm][fn] = __builtin_amdgcn_mfma_f32_16x16x32_bf16(
              af[fm], bf_[fn], acc[fm][fn], 0, 0, 0);
    }

    if (PASS == 1) {
      float msk[4];
      #pragma unroll
      for (int fn = 0; fn < 4; ++fn)
        msk[fn] = (n0 + wn * 64 + fn * 16 + rl < NTOT) ? 1.0f : 0.0f;
      #pragma unroll
      for (int fm = 0; fm < 4; ++fm)
        #pragma unroll
        for (int j = 0; j < 4; ++j) {
          float s = 0.f;
          if (edge) {
            #pragma unroll
            for (int fn = 0; fn < 4; ++fn) s += msk[fn] * __expf(acc[fm][fn][j]);
          } else {
            #pragma unroll
            for (int fn = 0; fn < 4; ++fn) s += __expf(acc[fm][fn][j]);
          }
          s += __shfl_xor(s, 1);
          s += __shfl_xor(s, 2);
          if ((rl & 3) == 0)
            part[wm * 64 + fm * 16 + kg * 4 + j][wn * 4 + (rl >> 2)] = s;
        }
      __syncthreads();
      if (t < MCHUNK) {
        float s = 0.f;
        #pragma unroll
        for (int q = 0; q < 8; ++q) s += part[t][q];
        partial[(size_t)nb * BATCH + c * MCHUNK + t] = s;
      }
    } else {
      #pragma unroll
      for (int fm = 0; fm < 4; ++fm)
        #pragma unroll
        for (int j = 0; j < 4; ++j) {
          int row = wm * 64 + fm * 16 + kg * 4 + j;
          float l = lse_s[row];
          size_t base = (size_t)(c * MCHUNK + row) * NTOT;
          #pragma unroll
          for (int fn = 0; fn < 4; ++fn) {
            int cg = n0 + wn * 64 + fn * 16 + rl;
            float val = l - acc[fm][fn][j];
            if (!edge || cg < NTOT)
              __builtin_nontemporal_store(val, out + base + cg);
          }
        }
    }
  }
}

// lse[m] = log( sum_nb partial[nb][m] )
__global__ void reduce_lse_kernel(const float* __restrict__ partial,
                                  float* __restrict__ lse) {
  __shared__ float sb[256];
  int m = blockIdx.x;
  float s = 0.f;
  for (int nb = threadIdx.x; nb < NBLKS; nb += 256)
    s += partial[(size_t)nb * BATCH + m];
  sb[threadIdx.x] = s;
  __syncthreads();
  for (int k = 128; k > 0; k >>= 1) {
    if (threadIdx.x < k) sb[threadIdx.x] += sb[threadIdx.x + k];
    __syncthreads();
  }
  if (threadIdx.x == 0) lse[m] = logf(sb[0]);
}

extern "C" void kernel_launch(void* const* d_in, const int* in_sizes, int n_in,
                              void* d_out, int out_size, void* d_ws, size_t ws_size,
                              hipStream_t stream) {
  const int*   idx = (const int*)d_in[0];
  const float* W1  = (const float*)d_in[1];
  const float* W2  = (const float*)d_in[2];
  float* out = (float*)d_out;

  // ws layout: h swizzled (256KB) | lse (4KB) | bf16 W2 tiles (51.2MB, optional)
  unsigned short* hws  = (unsigned short*)d_ws;
  float*          lse  = (float*)((char*)d_ws + 262144);
  unsigned short* w2ws = (unsigned short*)((char*)d_ws + 262144 + 4096);
  const size_t need = 262144 + 4096 + (size_t)NBLKS * TILE_B;
  const bool ws2 = (ws_size >= need);

  // partials live at the head of d_out (6.4 MB), consumed by reduce_lse
  // before pass 2 overwrites every output element.
  float* partial = out;

  build_h_kernel<<<64, 256, 0, stream>>>(idx, W1, hws);
  if (ws2) {
    gemm_pass<1, true ><<<NBLKS, 256, 0, stream>>>(W2, hws, w2ws, partial, nullptr, nullptr);
    reduce_lse_kernel<<<BATCH, 256, 0, stream>>>(partial, lse);
    gemm_pass<2, true ><<<NBLKS, 256, 0, stream>>>(W2, hws, w2ws, nullptr, lse, out);
  } else {
    gemm_pass<1, false><<<NBLKS, 256, 0, stream>>>(W2, hws, w2ws, partial, nullptr, nullptr);
    reduce_lse_kernel<<<BATCH, 256, 0, stream>>>(partial, lse);
    gemm_pass<2, false><<<NBLKS, 256, 0, stream>>>(W2, hws, w2ws, nullptr, lse, out);
  }
}